// Round 1
// baseline (162.657 us; speedup 1.0000x reference)
//
#include <hip/hip_runtime.h>
#include <hip/hip_bf16.h>

// Problem constants (fixed by the reference's setup_inputs).
constexpr int N_NODES  = 100000;
constexpr int BATCH    = 256;
constexpr int NUM_RELS = 200;
constexpr int VEC      = 300;
constexpr int DIM      = 32;
constexpr int MODES    = 6;

constexpr int BLOCK        = 256;
constexpr int BM_WORDS     = (N_NODES + 31) / 32;     // 3125 words = 12.5 KB (LDS)
constexpr int RELS_PER_BLK = 8;
constexpr int NRB          = NUM_RELS / RELS_PER_BLK; // 25
static_assert(NUM_RELS % RELS_PER_BLK == 0, "rel blocks assume exact tiling");
constexpr int EDGE_BLKS    = 256;                     // one list segment per edge block
constexpr int CAP          = 64;                      // codes/segment: Poisson(20), P(>64)~1e-13
constexpr int HASHN        = 1024;                    // LDS hash slots (load factor 0.5)
constexpr unsigned HEMPTY  = 0xFFFFFFFFu;
constexpr int MAXM         = 512;                     // per-b match buffer in final phase
constexpr int NPROD        = NRB + EDGE_BLKS;         // 281 producer arrivals

// ---- dtype-generic scalar load ---------------------------------------------
template <typename T> __device__ __forceinline__ float ldf(const void* p, int i);
template <> __device__ __forceinline__ float ldf<float>(const void* p, int i) {
    return ((const float*)p)[i];
}
template <> __device__ __forceinline__ float ldf<__hip_bfloat16>(const void* p, int i) {
    return __bfloat162float(((const __hip_bfloat16*)p)[i]);
}

// ---- per-block bf16-vs-fp32 detect (one ballot on wave 0) ------------------
__device__ __forceinline__ void detect_dtype(const void* rel_vectors, int* sflag) {
    const int tid = threadIdx.x;
    if (tid < 64) {
        unsigned short p = ((const unsigned short*)rel_vectors)[tid];
        unsigned long long mk = __ballot(((p >> 7) & 0xFF) > 140);
        if (tid == 0) *sflag = (mk == 0ull);
    }
    __syncthreads();
}

// ---- LDS hash: node id -> packed (head_b+1 | (tail_b+1)<<16) ---------------
__device__ __forceinline__ void hinsert(unsigned* hkey, unsigned* hval, int node, unsigned v) {
    unsigned h = ((unsigned)node * 2654435761u) >> 22;   // top 10 bits
    for (;;) {
        unsigned prev = atomicCAS(&hkey[h], HEMPTY, (unsigned)node);
        if (prev == HEMPTY || prev == (unsigned)node) { atomicOr(&hval[h], v); return; }
        h = (h + 1) & (HASHN - 1);
    }
}
__device__ __forceinline__ unsigned hlookup(const unsigned* hkey, const unsigned* hval, int node) {
    unsigned h = ((unsigned)node * 2654435761u) >> 22;
    for (;;) {
        const unsigned k = hkey[h];
        if (k == (unsigned)node) return hval[h];
        if (k == HEMPTY) return 0u;
        h = (h + 1) & (HASHN - 1);
    }
}

// ---- rel phase: E_rel[r] = mlp2(rel_vectors[r]); Y_rel[m][r] = E_rel[r]@reld_W[m]+reld_b[m]
template <typename T>
__device__ __forceinline__ void rel_body(const void* rel_vectors, const void* W1, const void* b1,
                                         const void* W2, const void* b2,
                                         const void* reld_W, const void* reld_b,
                                         float* E_rel, float* Y_rel,
                                         float (*rv)[VEC], float (*e1)[DIM], float (*e2)[DIM],
                                         int r0) {
    const int tid = threadIdx.x;
    const int g = tid >> 5, d = tid & 31;
    const int r = r0 + g;                        // always < NUM_RELS (exact tiling)
    for (int v = d; v < VEC; v += 32) rv[g][v] = ldf<T>(rel_vectors, r * VEC + v);
    __syncthreads();
    float acc = ldf<T>(b1, d);
    for (int v = 0; v < VEC; ++v) acc += rv[g][v] * ldf<T>(W1, v * DIM + d);
    e1[g][d] = acc;
    __syncthreads();
    float a2 = ldf<T>(b2, d);
    for (int k = 0; k < DIM; ++k) a2 += e1[g][k] * ldf<T>(W2, k * DIM + d);
    e2[g][d] = a2;
    E_rel[r * DIM + d] = a2;
    __syncthreads();
    for (int m = 0; m < MODES; ++m) {
        float y = ldf<T>(reld_b, m * DIM + d);
        for (int k = 0; k < DIM; ++k) y += e2[g][k] * ldf<T>(reld_W, (m * DIM + k) * DIM + d);
        Y_rel[(m * NUM_RELS + r) * DIM + d] = y;
    }
}

// ---- per-b epilogue math (final phase) -------------------------------------
template <typename T>
__device__ __forceinline__ void epilogue_math(const float* cat,
                                              const void* conc_W, const void* conc_b,
                                              const void* fc_W, const void* fc_b,
                                              void* out, int b) {
    const int tid = threadIdx.x;
    if (tid < DIM) {
        float h = ldf<T>(conc_b, tid);
        for (int k = 0; k < 2 * DIM; ++k) h += cat[k] * ldf<T>(conc_W, k * DIM + tid);
        h = fmaxf(h, 0.f);
        float n2 = h * h;
        #pragma unroll
        for (int off = 16; off >= 1; off >>= 1) n2 += __shfl_xor(n2, off);
        const float g = h / fmaxf(sqrtf(n2), 1e-12f);
        float pr = g * ldf<T>(fc_W, tid);
        #pragma unroll
        for (int off = 16; off >= 1; off >>= 1) pr += __shfl_xor(pr, off);
        if (tid == 0) {
            const float o = pr + ldf<T>(fc_b, 0);
            if constexpr (sizeof(T) == 2) ((__hip_bfloat16*)out)[b] = __float2bfloat16(o);
            else                          ((float*)out)[b] = o;
        }
    }
}

// ---- FUSED kernel ----------------------------------------------------------
// bid < NRB           : rel MLP + per-mode transforms, arrive, exit.
// bid in [NRB, +EDGE) : edge scan -> write private list segment -> arrive ->
//                       spin until all 281 producers arrived (device-scope
//                       release/acquire via __threadfence + atomicAdd) ->
//                       run the per-b epilogue for b = eb.
// All 281 blocks are co-resident (21 KB LDS, 4 waves, low VGPR -> >=2
// blocks/CU => capacity 512 >= 281), so the spin cannot deadlock.
struct EdgeSmem {
    unsigned bm[BM_WORDS];
    unsigned hkey[HASHN];
    unsigned hval[HASHN];
    unsigned obuf[CAP];
    int ocnt;
};
struct RelSmem {
    float rv[RELS_PER_BLK][VEC];
    float e1[RELS_PER_BLK][DIM];
    float e2[RELS_PER_BLK][DIM];
    int sflag;
};
struct FinSmem {
    float    accf[MODES][DIM];
    float    totf[MODES];
    unsigned mbuf[MAXM];
    int      mcnt;
    float    cat[2 * DIM];
    int      sflag;
};

__global__ __launch_bounds__(BLOCK) void k_fused(
        const int* __restrict__ edge_src, const int* __restrict__ edge_dst,
        const int* __restrict__ edge_type,
        const int* __restrict__ head_ids, const int* __restrict__ tail_ids,
        const int* __restrict__ rel_labels,
        const void* rel_vectors, const void* W1, const void* b1,
        const void* W2, const void* b2, const void* reld_W, const void* reld_b,
        const void* conc_W, const void* conc_b, const void* fc_W, const void* fc_b,
        unsigned* list, unsigned* listcnt, float* E_rel, float* Y_rel,
        int* done, void* out, int n_edges) {
    union SmemU { RelSmem rel; EdgeSmem edge; FinSmem fin; };
    __shared__ SmemU s;
    const int bid = blockIdx.x, tid = threadIdx.x;

    if (bid < NRB) {
        detect_dtype(rel_vectors, &s.rel.sflag);
        const int r0 = bid * RELS_PER_BLK;
        if (s.rel.sflag)
            rel_body<__hip_bfloat16>(rel_vectors, W1, b1, W2, b2, reld_W, reld_b,
                                     E_rel, Y_rel, s.rel.rv, s.rel.e1, s.rel.e2, r0);
        else
            rel_body<float>(rel_vectors, W1, b1, W2, b2, reld_W, reld_b,
                            E_rel, Y_rel, s.rel.rv, s.rel.e1, s.rel.e2, r0);
        // release: make E_rel/Y_rel visible, then arrive
        __threadfence();
        __syncthreads();
        if (tid == 0) atomicAdd(done, 1);
        return;
    }

    // ---- edge phase ----
    const int eb = bid - NRB;
    for (int i = tid; i < BM_WORDS; i += BLOCK) s.edge.bm[i] = 0u;
    for (int i = tid; i < HASHN; i += BLOCK) { s.edge.hkey[i] = HEMPTY; s.edge.hval[i] = 0u; }
    if (tid == 0) s.edge.ocnt = 0;
    __syncthreads();
    if (tid < BATCH) {
        const int h = head_ids[tid], t = tail_ids[tid];
        atomicOr(&s.edge.bm[h >> 5], 1u << (h & 31));
        atomicOr(&s.edge.bm[t >> 5], 1u << (t & 31));
        hinsert(s.edge.hkey, s.edge.hval, h, (unsigned)(tid + 1));
        hinsert(s.edge.hkey, s.edge.hval, t, (unsigned)(tid + 1) << 16);
    }
    __syncthreads();

    auto emit = [&](unsigned code) {
        const int idx = atomicAdd(&s.edge.ocnt, 1);
        if (idx < CAP) s.edge.obuf[idx] = code;
    };
    auto classify = [&](int sn, int dn, unsigned bs, unsigned bd, int e) {
        const int t = edge_type[e];
        const unsigned ps = bs ? hlookup(s.edge.hkey, s.edge.hval, sn) : 0u;
        const unsigned pd = bd ? hlookup(s.edge.hkey, s.edge.hval, dn) : 0u;
        const int hbs = (int)(ps & 0xFFFFu) - 1, tbs = (int)(ps >> 16) - 1;
        const int hbd = (int)(pd & 0xFFFFu) - 1, tbd = (int)(pd >> 16) - 1;
        const bool m5 = (hbs >= 0) && (hbs == tbd);
        const bool m6 = (hbd >= 0) && (hbd == tbs);
        if (hbd >= 0)        emit(((m6 ? 5u : 0u) * BATCH + hbd) * NUM_RELS + t);
        if (hbs >= 0)        emit(((m5 ? 4u : 1u) * BATCH + hbs) * NUM_RELS + t);
        if (tbd >= 0 && !m5) emit((2u * BATCH + tbd) * NUM_RELS + t);
        if (tbs >= 0 && !m6) emit((3u * BATCH + tbs) * NUM_RELS + t);
    };

    const int n4 = n_edges >> 2;
    const int sstr = EDGE_BLKS * BLOCK;
    const int et = eb * BLOCK + tid;
    const int4* src4 = (const int4*)edge_src;
    const int4* dst4 = (const int4*)edge_dst;
    for (int i = et; i < n4; i += sstr) {
        const int4 s4 = src4[i];
        const int4 d4 = dst4[i];
        #pragma unroll
        for (int j = 0; j < 4; ++j) {
            const int sn = (&s4.x)[j];
            const int dn = (&d4.x)[j];
            const unsigned bs = (s.edge.bm[sn >> 5] >> (sn & 31)) & 1u;
            const unsigned bd = (s.edge.bm[dn >> 5] >> (dn & 31)) & 1u;
            if (!(bs | bd)) continue;            // ~99% of edges: 2 LDS reads only
            classify(sn, dn, bs, bd, i * 4 + j);
        }
    }
    const int rem = n_edges & 3;
    if (et < rem) {
        const int e = n4 * 4 + et;
        const int sn = edge_src[e], dn = edge_dst[e];
        const unsigned bs = (s.edge.bm[sn >> 5] >> (sn & 31)) & 1u;
        const unsigned bd = (s.edge.bm[dn >> 5] >> (dn & 31)) & 1u;
        if (bs | bd) classify(sn, dn, bs, bd, e);
    }
    __syncthreads();
    const int oc = min(s.edge.ocnt, CAP);
    if (tid == 0) listcnt[eb] = (unsigned)oc;    // unconditional: no pre-zero needed
    for (int i = tid; i < oc; i += BLOCK) list[i * EDGE_BLKS + eb] = s.edge.obuf[i];

    // ---- release + grid handshake ----
    __threadfence();                             // every thread flushes its stores
    __syncthreads();                             // all flushes done before arrival
    if (tid == 0) {
        atomicAdd(done, 1);                      // arrive (device-scope atomic)
        while (atomicAdd(done, 0) < NPROD)       // spin: one lane per block
            __builtin_amdgcn_s_sleep(2);
    }
    __syncthreads();
    __threadfence();                             // acquire: see all producers' data

    // ---- final phase: b = eb ----
    const int b = eb;
    for (int i = tid; i < MODES * DIM; i += BLOCK) ((float*)s.fin.accf)[i] = 0.f;
    if (tid < MODES) s.fin.totf[tid] = 0.f;
    if (tid == 0) s.fin.mcnt = 0;
    const int c = (int)listcnt[tid];             // coalesced: thread t owns segment t
    detect_dtype(rel_vectors, &s.fin.sflag);     // includes __syncthreads

    // phase 1: all 256 segments scanned in parallel; round i is a coalesced
    // 1 KB load across the block. Typical c ~ 20, max ~ 45.
    for (int i = 0; i < c; ++i) {
        const unsigned code = list[i * EDGE_BLKS + tid];
        const int bb = (int)((code / NUM_RELS) % BATCH);
        if (bb == b) {
            const int k = atomicAdd(&s.fin.mcnt, 1);
            if (k < MAXM) s.fin.mbuf[k] = code;
        }
    }
    __syncthreads();

    // phase 2: accumulate matched Y_rel rows; 8 half-wave groups over matches
    const int mc = min(s.fin.mcnt, MAXM);
    const int d = tid & 31;
    for (int j = tid >> 5; j < mc; j += 8) {
        const unsigned code = s.fin.mbuf[j];
        const int m = (int)(code / (NUM_RELS * BATCH));
        const int t = (int)(code % NUM_RELS);
        atomicAdd(&s.fin.accf[m][d], Y_rel[(m * NUM_RELS + t) * DIM + d]);
        if (d == 0) atomicAdd(&s.fin.totf[m], 1.f);
    }
    __syncthreads();

    if (tid < DIM) {
        float rn = 0.f;
        for (int m = 0; m < MODES; ++m) rn += s.fin.accf[m][tid] / (s.fin.totf[m] + 1e-30f);
        s.fin.cat[tid] = rn / (float)MODES;
        s.fin.cat[DIM + tid] = E_rel[rel_labels[b] * DIM + tid];
    }
    __syncthreads();
    if (s.fin.sflag) epilogue_math<__hip_bfloat16>(s.fin.cat, conc_W, conc_b, fc_W, fc_b, out, b);
    else             epilogue_math<float>(s.fin.cat, conc_W, conc_b, fc_W, fc_b, out, b);
}

extern "C" void kernel_launch(void* const* d_in, const int* in_sizes, int n_in,
                              void* d_out, int out_size, void* d_ws, size_t ws_size,
                              hipStream_t stream) {
    const int* edge_src   = (const int*)d_in[0];
    const int* edge_dst   = (const int*)d_in[1];
    const int* edge_type  = (const int*)d_in[2];
    const int* head_ids   = (const int*)d_in[3];
    const int* tail_ids   = (const int*)d_in[4];
    const int* rel_labels = (const int*)d_in[5];
    const void* rel_vectors = d_in[6];
    const void* W1     = d_in[7];
    const void* b1     = d_in[8];
    const void* W2     = d_in[9];
    const void* b2     = d_in[10];
    const void* reld_W = d_in[11];
    const void* reld_b = d_in[12];
    const void* conc_W = d_in[13];
    const void* conc_b = d_in[14];
    const void* fc_W   = d_in[15];
    const void* fc_b   = d_in[16];

    const int n_edges = in_sizes[0];

    // workspace layout (~245 KB of ws; everything consumed is written first,
    // except `done` which is zeroed by the 4-byte memset below)
    unsigned* list    = (unsigned*)d_ws;                 // CAP * EDGE_BLKS (transposed)
    unsigned* listcnt = list + EDGE_BLKS * CAP;          // EDGE_BLKS
    float*    E_rel   = (float*)(listcnt + EDGE_BLKS);   // NUM_RELS*DIM
    float*    Y_rel   = E_rel + NUM_RELS * DIM;          // MODES*NUM_RELS*DIM
    int*      done    = (int*)(Y_rel + MODES * NUM_RELS * DIM); // 1 word arrival counter

    hipMemsetAsync(done, 0, sizeof(int), stream);        // ws is poisoned each iter
    k_fused<<<NRB + EDGE_BLKS, BLOCK, 0, stream>>>(
        edge_src, edge_dst, edge_type, head_ids, tail_ids, rel_labels,
        rel_vectors, W1, b1, W2, b2, reld_W, reld_b,
        conc_W, conc_b, fc_W, fc_b,
        list, listcnt, E_rel, Y_rel, done, d_out, n_edges);
}

// Round 3
// 124.383 us; speedup vs baseline: 1.3077x; 1.3077x over previous
//
#include <hip/hip_runtime.h>
#include <hip/hip_bf16.h>

// Problem constants (fixed by the reference's setup_inputs).
constexpr int N_NODES  = 100000;
constexpr int BATCH    = 256;
constexpr int NUM_RELS = 200;
constexpr int VEC      = 300;
constexpr int DIM      = 32;
constexpr int MODES    = 6;

constexpr int BLOCK        = 256;
constexpr int BM_WORDS     = (N_NODES + 31) / 32;     // 3125 words = 12.5 KB (LDS)
constexpr int RELS_PER_BLK = 8;
constexpr int NRB          = NUM_RELS / RELS_PER_BLK; // 25
static_assert(NUM_RELS % RELS_PER_BLK == 0, "rel blocks assume exact tiling");
constexpr int EDGE_BLKS    = 256;                     // one list segment per edge block
constexpr int CAP          = 64;                      // codes/segment: Poisson(20), P(>64)~1e-13
constexpr int HASHN        = 1024;                    // LDS hash slots (load factor 0.5)
constexpr unsigned HEMPTY  = 0xFFFFFFFFu;
constexpr int MAXM         = 512;                     // per-b match buffer in final phase
constexpr int NPROD        = NRB + EDGE_BLKS;         // 281 producer arrivals

// ---- agent-scope coherent accessors ----------------------------------------
// sc0+sc1 write-through stores / cache-bypassing loads. Because every
// cross-block word moves through these, NOTHING cross-block is ever dirty in
// an L2 => no buffer_wbl2 / buffer_inv (i.e. no __threadfence) is needed.
// Release ordering is s_waitcnt vmcnt(0) + __syncthreads before the arrival.
__device__ __forceinline__ void st_agent(float* p, float v) {
    __hip_atomic_store(p, v, __ATOMIC_RELAXED, __HIP_MEMORY_SCOPE_AGENT);
}
__device__ __forceinline__ void st_agent(unsigned* p, unsigned v) {
    __hip_atomic_store(p, v, __ATOMIC_RELAXED, __HIP_MEMORY_SCOPE_AGENT);
}
__device__ __forceinline__ float ld_agent_f(const float* p) {
    return __hip_atomic_load(p, __ATOMIC_RELAXED, __HIP_MEMORY_SCOPE_AGENT);
}
__device__ __forceinline__ unsigned ld_agent_u(const unsigned* p) {
    return __hip_atomic_load(p, __ATOMIC_RELAXED, __HIP_MEMORY_SCOPE_AGENT);
}

// ---- dtype-generic scalar load ---------------------------------------------
template <typename T> __device__ __forceinline__ float ldf(const void* p, int i);
template <> __device__ __forceinline__ float ldf<float>(const void* p, int i) {
    return ((const float*)p)[i];
}
template <> __device__ __forceinline__ float ldf<__hip_bfloat16>(const void* p, int i) {
    return __bfloat162float(((const __hip_bfloat16*)p)[i]);
}

// ---- per-block bf16-vs-fp32 detect (one ballot on wave 0) ------------------
__device__ __forceinline__ void detect_dtype(const void* rel_vectors, int* sflag) {
    const int tid = threadIdx.x;
    if (tid < 64) {
        unsigned short p = ((const unsigned short*)rel_vectors)[tid];
        unsigned long long mk = __ballot(((p >> 7) & 0xFF) > 140);
        if (tid == 0) *sflag = (mk == 0ull);
    }
    __syncthreads();
}

// ---- LDS hash: node id -> packed (head_b+1 | (tail_b+1)<<16) ---------------
__device__ __forceinline__ void hinsert(unsigned* hkey, unsigned* hval, int node, unsigned v) {
    unsigned h = ((unsigned)node * 2654435761u) >> 22;   // top 10 bits
    for (;;) {
        unsigned prev = atomicCAS(&hkey[h], HEMPTY, (unsigned)node);
        if (prev == HEMPTY || prev == (unsigned)node) { atomicOr(&hval[h], v); return; }
        h = (h + 1) & (HASHN - 1);
    }
}
__device__ __forceinline__ unsigned hlookup(const unsigned* hkey, const unsigned* hval, int node) {
    unsigned h = ((unsigned)node * 2654435761u) >> 22;
    for (;;) {
        const unsigned k = hkey[h];
        if (k == (unsigned)node) return hval[h];
        if (k == HEMPTY) return 0u;
        h = (h + 1) & (HASHN - 1);
    }
}

// ---- rel phase: E_rel[r] = mlp2(rel_vectors[r]); Y_rel[m][r] = E_rel[r]@reld_W[m]+reld_b[m]
// Cross-block outputs written with agent-scope coherent stores.
template <typename T>
__device__ __forceinline__ void rel_body(const void* rel_vectors, const void* W1, const void* b1,
                                         const void* W2, const void* b2,
                                         const void* reld_W, const void* reld_b,
                                         float* E_rel, float* Y_rel,
                                         float (*rv)[VEC], float (*e1)[DIM], float (*e2)[DIM],
                                         int r0) {
    const int tid = threadIdx.x;
    const int g = tid >> 5, d = tid & 31;
    const int r = r0 + g;                        // always < NUM_RELS (exact tiling)
    for (int v = d; v < VEC; v += 32) rv[g][v] = ldf<T>(rel_vectors, r * VEC + v);
    __syncthreads();
    float acc = ldf<T>(b1, d);
    for (int v = 0; v < VEC; ++v) acc += rv[g][v] * ldf<T>(W1, v * DIM + d);
    e1[g][d] = acc;
    __syncthreads();
    float a2 = ldf<T>(b2, d);
    for (int k = 0; k < DIM; ++k) a2 += e1[g][k] * ldf<T>(W2, k * DIM + d);
    e2[g][d] = a2;
    st_agent(&E_rel[r * DIM + d], a2);
    __syncthreads();
    for (int m = 0; m < MODES; ++m) {
        float y = ldf<T>(reld_b, m * DIM + d);
        for (int k = 0; k < DIM; ++k) y += e2[g][k] * ldf<T>(reld_W, (m * DIM + k) * DIM + d);
        st_agent(&Y_rel[(m * NUM_RELS + r) * DIM + d], y);
    }
}

// ---- per-b epilogue math (final phase) -------------------------------------
template <typename T>
__device__ __forceinline__ void epilogue_math(const float* cat,
                                              const void* conc_W, const void* conc_b,
                                              const void* fc_W, const void* fc_b,
                                              void* out, int b) {
    const int tid = threadIdx.x;
    if (tid < DIM) {
        float h = ldf<T>(conc_b, tid);
        for (int k = 0; k < 2 * DIM; ++k) h += cat[k] * ldf<T>(conc_W, k * DIM + tid);
        h = fmaxf(h, 0.f);
        float n2 = h * h;
        #pragma unroll
        for (int off = 16; off >= 1; off >>= 1) n2 += __shfl_xor(n2, off);
        const float g = h / fmaxf(sqrtf(n2), 1e-12f);
        float pr = g * ldf<T>(fc_W, tid);
        #pragma unroll
        for (int off = 16; off >= 1; off >>= 1) pr += __shfl_xor(pr, off);
        if (tid == 0) {
            const float o = pr + ldf<T>(fc_b, 0);
            if constexpr (sizeof(T) == 2) ((__hip_bfloat16*)out)[b] = __float2bfloat16(o);
            else                          ((float*)out)[b] = o;
        }
    }
}

// ---- FUSED kernel, fence-free release + RMW-poll handshake ------------------
// bid < NRB           : rel MLP + per-mode transforms (coherent stores), arrive, exit.
// bid in [NRB, +EDGE) : edge scan -> coherent list stores -> arrive ->
//                       tid0 polls `done` with agent-scope RMW fetch_add(0)
//                       (executes at the coherence point: can NEVER read a
//                       stale value and can never hang; proven correct in the
//                       round-1 run) + s_sleep(8) backoff -> per-b epilogue
//                       (b = eb) reading cross-block data with agent loads.
// NO __threadfence anywhere => no buffer_wbl2/buffer_inv L2 tag-walks, which
// the round-1 counters indicate cost ~65 us across 281 blocks.
// All 281 blocks are co-resident (21 KB LDS, 44 VGPR => 7 blocks/CU capacity,
// 1792 slots >= 281), so the wait always terminates.
struct EdgeSmem {
    unsigned bm[BM_WORDS];
    unsigned hkey[HASHN];
    unsigned hval[HASHN];
    unsigned obuf[CAP];
    int ocnt;
};
struct RelSmem {
    float rv[RELS_PER_BLK][VEC];
    float e1[RELS_PER_BLK][DIM];
    float e2[RELS_PER_BLK][DIM];
    int sflag;
};
struct FinSmem {
    float    accf[MODES][DIM];
    float    totf[MODES];
    unsigned mbuf[MAXM];
    int      mcnt;
    float    cat[2 * DIM];
    int      sflag;
};

__global__ __launch_bounds__(BLOCK) void k_fused(
        const int* __restrict__ edge_src, const int* __restrict__ edge_dst,
        const int* __restrict__ edge_type,
        const int* __restrict__ head_ids, const int* __restrict__ tail_ids,
        const int* __restrict__ rel_labels,
        const void* rel_vectors, const void* W1, const void* b1,
        const void* W2, const void* b2, const void* reld_W, const void* reld_b,
        const void* conc_W, const void* conc_b, const void* fc_W, const void* fc_b,
        unsigned* list, unsigned* listcnt, float* E_rel, float* Y_rel,
        int* done, void* out, int n_edges) {
    union SmemU { RelSmem rel; EdgeSmem edge; FinSmem fin; };
    __shared__ SmemU s;
    const int bid = blockIdx.x, tid = threadIdx.x;

    if (bid < NRB) {
        detect_dtype(rel_vectors, &s.rel.sflag);
        const int r0 = bid * RELS_PER_BLK;
        if (s.rel.sflag)
            rel_body<__hip_bfloat16>(rel_vectors, W1, b1, W2, b2, reld_W, reld_b,
                                     E_rel, Y_rel, s.rel.rv, s.rel.e1, s.rel.e2, r0);
        else
            rel_body<float>(rel_vectors, W1, b1, W2, b2, reld_W, reld_b,
                            E_rel, Y_rel, s.rel.rv, s.rel.e1, s.rel.e2, r0);
        // release: every thread drains its write-through stores, barrier, arrive
        asm volatile("s_waitcnt vmcnt(0)" ::: "memory");
        __syncthreads();
        if (tid == 0)
            __hip_atomic_fetch_add(done, 1, __ATOMIC_RELAXED, __HIP_MEMORY_SCOPE_AGENT);
        return;
    }

    // ---- edge phase ----
    const int eb = bid - NRB;
    for (int i = tid; i < BM_WORDS; i += BLOCK) s.edge.bm[i] = 0u;
    for (int i = tid; i < HASHN; i += BLOCK) { s.edge.hkey[i] = HEMPTY; s.edge.hval[i] = 0u; }
    if (tid == 0) s.edge.ocnt = 0;
    __syncthreads();
    if (tid < BATCH) {
        const int h = head_ids[tid], t = tail_ids[tid];
        atomicOr(&s.edge.bm[h >> 5], 1u << (h & 31));
        atomicOr(&s.edge.bm[t >> 5], 1u << (t & 31));
        hinsert(s.edge.hkey, s.edge.hval, h, (unsigned)(tid + 1));
        hinsert(s.edge.hkey, s.edge.hval, t, (unsigned)(tid + 1) << 16);
    }
    __syncthreads();

    auto emit = [&](unsigned code) {
        const int idx = atomicAdd(&s.edge.ocnt, 1);
        if (idx < CAP) s.edge.obuf[idx] = code;
    };
    auto classify = [&](int sn, int dn, unsigned bs, unsigned bd, int e) {
        const int t = edge_type[e];
        const unsigned ps = bs ? hlookup(s.edge.hkey, s.edge.hval, sn) : 0u;
        const unsigned pd = bd ? hlookup(s.edge.hkey, s.edge.hval, dn) : 0u;
        const int hbs = (int)(ps & 0xFFFFu) - 1, tbs = (int)(ps >> 16) - 1;
        const int hbd = (int)(pd & 0xFFFFu) - 1, tbd = (int)(pd >> 16) - 1;
        const bool m5 = (hbs >= 0) && (hbs == tbd);
        const bool m6 = (hbd >= 0) && (hbd == tbs);
        if (hbd >= 0)        emit(((m6 ? 5u : 0u) * BATCH + hbd) * NUM_RELS + t);
        if (hbs >= 0)        emit(((m5 ? 4u : 1u) * BATCH + hbs) * NUM_RELS + t);
        if (tbd >= 0 && !m5) emit((2u * BATCH + tbd) * NUM_RELS + t);
        if (tbs >= 0 && !m6) emit((3u * BATCH + tbs) * NUM_RELS + t);
    };

    const int n4 = n_edges >> 2;
    const int sstr = EDGE_BLKS * BLOCK;
    const int et = eb * BLOCK + tid;
    const int4* src4 = (const int4*)edge_src;
    const int4* dst4 = (const int4*)edge_dst;
    for (int i = et; i < n4; i += sstr) {
        const int4 s4 = src4[i];
        const int4 d4 = dst4[i];
        #pragma unroll
        for (int j = 0; j < 4; ++j) {
            const int sn = (&s4.x)[j];
            const int dn = (&d4.x)[j];
            const unsigned bs = (s.edge.bm[sn >> 5] >> (sn & 31)) & 1u;
            const unsigned bd = (s.edge.bm[dn >> 5] >> (dn & 31)) & 1u;
            if (!(bs | bd)) continue;            // ~99% of edges: 2 LDS reads only
            classify(sn, dn, bs, bd, i * 4 + j);
        }
    }
    const int rem = n_edges & 3;
    if (et < rem) {
        const int e = n4 * 4 + et;
        const int sn = edge_src[e], dn = edge_dst[e];
        const unsigned bs = (s.edge.bm[sn >> 5] >> (sn & 31)) & 1u;
        const unsigned bd = (s.edge.bm[dn >> 5] >> (dn & 31)) & 1u;
        if (bs | bd) classify(sn, dn, bs, bd, e);
    }
    __syncthreads();
    const int oc = min(s.edge.ocnt, CAP);
    if (tid == 0) st_agent(&listcnt[eb], (unsigned)oc);  // unconditional: no pre-zero needed
    for (int i = tid; i < oc; i += BLOCK) st_agent(&list[i * EDGE_BLKS + eb], s.edge.obuf[i]);

    // ---- fence-free release + grid handshake (RMW poll: stale-proof) ----
    asm volatile("s_waitcnt vmcnt(0)" ::: "memory");     // my coherent stores retired
    __syncthreads();                                     // all waves' stores retired
    if (tid == 0) {
        __hip_atomic_fetch_add(done, 1, __ATOMIC_RELAXED, __HIP_MEMORY_SCOPE_AGENT);
        while (__hip_atomic_fetch_add(done, 0, __ATOMIC_RELAXED,
                                      __HIP_MEMORY_SCOPE_AGENT) < NPROD)
            __builtin_amdgcn_s_sleep(8);                 // ~512 cy backoff between RMW polls
    }
    __syncthreads();

    // ---- final phase: b = eb (all cross-block reads are agent-scope) ----
    const int b = eb;
    for (int i = tid; i < MODES * DIM; i += BLOCK) ((float*)s.fin.accf)[i] = 0.f;
    if (tid < MODES) s.fin.totf[tid] = 0.f;
    if (tid == 0) s.fin.mcnt = 0;
    const int c = (int)ld_agent_u(&listcnt[tid]);        // coalesced: thread t owns segment t
    detect_dtype(rel_vectors, &s.fin.sflag);             // includes __syncthreads

    // phase 1: all 256 segments scanned in parallel; round i is a coalesced
    // 1 KB load across the block. Typical c ~ 20, max ~ 45.
    for (int i = 0; i < c; ++i) {
        const unsigned code = ld_agent_u(&list[i * EDGE_BLKS + tid]);
        const int bb = (int)((code / NUM_RELS) % BATCH);
        if (bb == b) {
            const int k = atomicAdd(&s.fin.mcnt, 1);
            if (k < MAXM) s.fin.mbuf[k] = code;
        }
    }
    __syncthreads();

    // phase 2: accumulate matched Y_rel rows; 8 half-wave groups over matches
    const int mc = min(s.fin.mcnt, MAXM);
    const int d = tid & 31;
    for (int j = tid >> 5; j < mc; j += 8) {
        const unsigned code = s.fin.mbuf[j];
        const int m = (int)(code / (NUM_RELS * BATCH));
        const int t = (int)(code % NUM_RELS);
        atomicAdd(&s.fin.accf[m][d], ld_agent_f(&Y_rel[(m * NUM_RELS + t) * DIM + d]));
        if (d == 0) atomicAdd(&s.fin.totf[m], 1.f);
    }
    __syncthreads();

    if (tid < DIM) {
        float rn = 0.f;
        for (int m = 0; m < MODES; ++m) rn += s.fin.accf[m][tid] / (s.fin.totf[m] + 1e-30f);
        s.fin.cat[tid] = rn / (float)MODES;
        s.fin.cat[DIM + tid] = ld_agent_f(&E_rel[rel_labels[b] * DIM + tid]);
    }
    __syncthreads();
    if (s.fin.sflag) epilogue_math<__hip_bfloat16>(s.fin.cat, conc_W, conc_b, fc_W, fc_b, out, b);
    else             epilogue_math<float>(s.fin.cat, conc_W, conc_b, fc_W, fc_b, out, b);
}

extern "C" void kernel_launch(void* const* d_in, const int* in_sizes, int n_in,
                              void* d_out, int out_size, void* d_ws, size_t ws_size,
                              hipStream_t stream) {
    const int* edge_src   = (const int*)d_in[0];
    const int* edge_dst   = (const int*)d_in[1];
    const int* edge_type  = (const int*)d_in[2];
    const int* head_ids   = (const int*)d_in[3];
    const int* tail_ids   = (const int*)d_in[4];
    const int* rel_labels = (const int*)d_in[5];
    const void* rel_vectors = d_in[6];
    const void* W1     = d_in[7];
    const void* b1     = d_in[8];
    const void* W2     = d_in[9];
    const void* b2     = d_in[10];
    const void* reld_W = d_in[11];
    const void* reld_b = d_in[12];
    const void* conc_W = d_in[13];
    const void* conc_b = d_in[14];
    const void* fc_W   = d_in[15];
    const void* fc_b   = d_in[16];

    const int n_edges = in_sizes[0];

    // workspace layout (~245 KB of ws; everything consumed is written first,
    // except `done` which is zeroed by the 4-byte memset below)
    unsigned* list    = (unsigned*)d_ws;                 // CAP * EDGE_BLKS (transposed)
    unsigned* listcnt = list + EDGE_BLKS * CAP;          // EDGE_BLKS
    float*    E_rel   = (float*)(listcnt + EDGE_BLKS);   // NUM_RELS*DIM
    float*    Y_rel   = E_rel + NUM_RELS * DIM;          // MODES*NUM_RELS*DIM
    int*      done    = (int*)(Y_rel + MODES * NUM_RELS * DIM); // 1 word arrival counter

    hipMemsetAsync(done, 0, sizeof(int), stream);        // ws is poisoned each iter
    k_fused<<<NRB + EDGE_BLKS, BLOCK, 0, stream>>>(
        edge_src, edge_dst, edge_type, head_ids, tail_ids, rel_labels,
        rel_vectors, W1, b1, W2, b2, reld_W, reld_b,
        conc_W, conc_b, fc_W, fc_b,
        list, listcnt, E_rel, Y_rel, done, d_out, n_edges);
}

// Round 4
// 118.848 us; speedup vs baseline: 1.3686x; 1.0466x over previous
//
#include <hip/hip_runtime.h>
#include <hip/hip_bf16.h>

// Problem constants (fixed by the reference's setup_inputs).
constexpr int N_NODES  = 100000;
constexpr int BATCH    = 256;
constexpr int NUM_RELS = 200;
constexpr int VEC      = 300;
constexpr int DIM      = 32;
constexpr int MODES    = 6;

constexpr int BLOCK        = 256;
constexpr int BM_WORDS     = (N_NODES + 31) / 32;     // 3125 words = 12.5 KB (LDS)
constexpr int RELS_PER_BLK = 8;
constexpr int NRB          = NUM_RELS / RELS_PER_BLK; // 25
static_assert(NUM_RELS % RELS_PER_BLK == 0, "rel blocks assume exact tiling");
constexpr int EDGE_BLKS    = 256;
constexpr int HASHN        = 1024;                    // LDS hash slots (load factor 0.5)
constexpr unsigned HEMPTY  = 0xFFFFFFFFu;
constexpr int MAXB         = 128;                     // codes per b: Poisson(~20), P(>128)~0
constexpr unsigned NPROD   = NRB + EDGE_BLKS;         // 281 producer arrivals

// ---- agent-scope coherent accessors ----------------------------------------
// sc0+sc1 write-through stores / cache-bypassing loads. Every cross-block word
// moves through these => nothing cross-block is ever dirty in an L2 => no
// buffer_wbl2/buffer_inv (no __threadfence) needed anywhere. Release ordering
// is s_waitcnt vmcnt(0) + __syncthreads before the arrival add. This protocol
// is HW-proven by round 3 (passed, absmax 0).
__device__ __forceinline__ void st_agent(float* p, float v) {
    __hip_atomic_store(p, v, __ATOMIC_RELAXED, __HIP_MEMORY_SCOPE_AGENT);
}
__device__ __forceinline__ void st_agent(unsigned* p, unsigned v) {
    __hip_atomic_store(p, v, __ATOMIC_RELAXED, __HIP_MEMORY_SCOPE_AGENT);
}
__device__ __forceinline__ float ld_agent_f(const float* p) {
    return __hip_atomic_load(p, __ATOMIC_RELAXED, __HIP_MEMORY_SCOPE_AGENT);
}
__device__ __forceinline__ unsigned ld_agent_u(const unsigned* p) {
    return __hip_atomic_load(p, __ATOMIC_RELAXED, __HIP_MEMORY_SCOPE_AGENT);
}

// ---- dtype-generic scalar load ---------------------------------------------
template <typename T> __device__ __forceinline__ float ldf(const void* p, int i);
template <> __device__ __forceinline__ float ldf<float>(const void* p, int i) {
    return ((const float*)p)[i];
}
template <> __device__ __forceinline__ float ldf<__hip_bfloat16>(const void* p, int i) {
    return __bfloat162float(((const __hip_bfloat16*)p)[i]);
}

// ---- per-block bf16-vs-fp32 detect (one ballot on wave 0) ------------------
__device__ __forceinline__ void detect_dtype(const void* rel_vectors, int* sflag) {
    const int tid = threadIdx.x;
    if (tid < 64) {
        unsigned short p = ((const unsigned short*)rel_vectors)[tid];
        unsigned long long mk = __ballot(((p >> 7) & 0xFF) > 140);
        if (tid == 0) *sflag = (mk == 0ull);
    }
    __syncthreads();
}

// ---- LDS hash: node id -> packed (head_b+1 | (tail_b+1)<<16) ---------------
__device__ __forceinline__ void hinsert(unsigned* hkey, unsigned* hval, int node, unsigned v) {
    unsigned h = ((unsigned)node * 2654435761u) >> 22;   // top 10 bits
    for (;;) {
        unsigned prev = atomicCAS(&hkey[h], HEMPTY, (unsigned)node);
        if (prev == HEMPTY || prev == (unsigned)node) { atomicOr(&hval[h], v); return; }
        h = (h + 1) & (HASHN - 1);
    }
}
__device__ __forceinline__ unsigned hlookup(const unsigned* hkey, const unsigned* hval, int node) {
    unsigned h = ((unsigned)node * 2654435761u) >> 22;
    for (;;) {
        const unsigned k = hkey[h];
        if (k == (unsigned)node) return hval[h];
        if (k == HEMPTY) return 0u;
        h = (h + 1) & (HASHN - 1);
    }
}

// ---- rel phase: E_rel[r] = mlp2(rel_vectors[r]); Y_rel[m][r] = E_rel[r]@reld_W[m]+reld_b[m]
template <typename T>
__device__ __forceinline__ void rel_body(const void* rel_vectors, const void* W1, const void* b1,
                                         const void* W2, const void* b2,
                                         const void* reld_W, const void* reld_b,
                                         float* E_rel, float* Y_rel,
                                         float (*rv)[VEC], float (*e1)[DIM], float (*e2)[DIM],
                                         int r0) {
    const int tid = threadIdx.x;
    const int g = tid >> 5, d = tid & 31;
    const int r = r0 + g;                        // always < NUM_RELS (exact tiling)
    for (int v = d; v < VEC; v += 32) rv[g][v] = ldf<T>(rel_vectors, r * VEC + v);
    __syncthreads();
    float acc = ldf<T>(b1, d);
    for (int v = 0; v < VEC; ++v) acc += rv[g][v] * ldf<T>(W1, v * DIM + d);
    e1[g][d] = acc;
    __syncthreads();
    float a2 = ldf<T>(b2, d);
    for (int k = 0; k < DIM; ++k) a2 += e1[g][k] * ldf<T>(W2, k * DIM + d);
    e2[g][d] = a2;
    st_agent(&E_rel[r * DIM + d], a2);
    __syncthreads();
    for (int m = 0; m < MODES; ++m) {
        float y = ldf<T>(reld_b, m * DIM + d);
        for (int k = 0; k < DIM; ++k) y += e2[g][k] * ldf<T>(reld_W, (m * DIM + k) * DIM + d);
        st_agent(&Y_rel[(m * NUM_RELS + r) * DIM + d], y);
    }
}

// ---- per-b epilogue math (final phase) -------------------------------------
template <typename T>
__device__ __forceinline__ void epilogue_math(const float* cat,
                                              const void* conc_W, const void* conc_b,
                                              const void* fc_W, const void* fc_b,
                                              void* out, int b) {
    const int tid = threadIdx.x;
    if (tid < DIM) {
        float h = ldf<T>(conc_b, tid);
        for (int k = 0; k < 2 * DIM; ++k) h += cat[k] * ldf<T>(conc_W, k * DIM + tid);
        h = fmaxf(h, 0.f);
        float n2 = h * h;
        #pragma unroll
        for (int off = 16; off >= 1; off >>= 1) n2 += __shfl_xor(n2, off);
        const float g = h / fmaxf(sqrtf(n2), 1e-12f);
        float pr = g * ldf<T>(fc_W, tid);
        #pragma unroll
        for (int off = 16; off >= 1; off >>= 1) pr += __shfl_xor(pr, off);
        if (tid == 0) {
            const float o = pr + ldf<T>(fc_b, 0);
            if constexpr (sizeof(T) == 2) ((__hip_bfloat16*)out)[b] = __float2bfloat16(o);
            else                          ((float*)out)[b] = o;
        }
    }
}

// ---- FUSED kernel, per-b bucket routing ------------------------------------
// bid < NRB           : rel MLP + per-mode transforms (coherent stores), arrive, exit.
// bid in [NRB, +EDGE) : edge scan; each classified edge emits its code DIRECTLY
//                       into the target b's global bucket (agent fetch_add on
//                       bcnt[bb] + agent store). No per-block list, and — key
//                       change vs round 3 — NO O(total-codes) scan per final
//                       block: final block b reads its own <=~45 codes in ONE
//                       parallel round instead of ~45 serialized ~600ns
//                       uncached loads (the ~25-30us latency hole round 3's
//                       counters exposed: 42us kernel, 2.3% VALUBusy, 1% HBM).
// Handshake: proven agent-RMW arrive/poll; final-phase LDS prep + dtype detect
// hoisted BEFORE the spin to hide under the wait.
// All 281 blocks co-resident (21 KB LDS, 4 waves => 7 blocks/CU capacity).
struct EdgeSmem {
    unsigned bm[BM_WORDS];
    unsigned hkey[HASHN];
    unsigned hval[HASHN];
};
struct RelSmem {
    float rv[RELS_PER_BLK][VEC];
    float e1[RELS_PER_BLK][DIM];
    float e2[RELS_PER_BLK][DIM];
    int sflag;
};
struct FinSmem {
    float    accf[MODES][DIM];
    float    totf[MODES];
    unsigned mbuf[MAXB];
    float    cat[2 * DIM];
    int      sflag;
};

__global__ __launch_bounds__(BLOCK) void k_fused(
        const int* __restrict__ edge_src, const int* __restrict__ edge_dst,
        const int* __restrict__ edge_type,
        const int* __restrict__ head_ids, const int* __restrict__ tail_ids,
        const int* __restrict__ rel_labels,
        const void* rel_vectors, const void* W1, const void* b1,
        const void* W2, const void* b2, const void* reld_W, const void* reld_b,
        const void* conc_W, const void* conc_b, const void* fc_W, const void* fc_b,
        unsigned* bucket, unsigned* bcnt, float* E_rel, float* Y_rel,
        unsigned* done, void* out, int n_edges) {
    union SmemU { RelSmem rel; EdgeSmem edge; FinSmem fin; };
    __shared__ SmemU s;
    const int bid = blockIdx.x, tid = threadIdx.x;

    if (bid < NRB) {
        detect_dtype(rel_vectors, &s.rel.sflag);
        const int r0 = bid * RELS_PER_BLK;
        if (s.rel.sflag)
            rel_body<__hip_bfloat16>(rel_vectors, W1, b1, W2, b2, reld_W, reld_b,
                                     E_rel, Y_rel, s.rel.rv, s.rel.e1, s.rel.e2, r0);
        else
            rel_body<float>(rel_vectors, W1, b1, W2, b2, reld_W, reld_b,
                            E_rel, Y_rel, s.rel.rv, s.rel.e1, s.rel.e2, r0);
        // release: every thread drains its write-through stores, barrier, arrive
        asm volatile("s_waitcnt vmcnt(0)" ::: "memory");
        __syncthreads();
        if (tid == 0)
            __hip_atomic_fetch_add(done, 1u, __ATOMIC_RELAXED, __HIP_MEMORY_SCOPE_AGENT);
        return;
    }

    // ---- edge phase ----
    const int eb = bid - NRB;
    for (int i = tid; i < BM_WORDS; i += BLOCK) s.edge.bm[i] = 0u;
    for (int i = tid; i < HASHN; i += BLOCK) { s.edge.hkey[i] = HEMPTY; s.edge.hval[i] = 0u; }
    __syncthreads();
    if (tid < BATCH) {
        const int h = head_ids[tid], t = tail_ids[tid];
        atomicOr(&s.edge.bm[h >> 5], 1u << (h & 31));
        atomicOr(&s.edge.bm[t >> 5], 1u << (t & 31));
        hinsert(s.edge.hkey, s.edge.hval, h, (unsigned)(tid + 1));
        hinsert(s.edge.hkey, s.edge.hval, t, (unsigned)(tid + 1) << 16);
    }
    __syncthreads();

    // emit a (mode, rel) code straight into target b's bucket (agent scope)
    auto emit = [&](int bb, unsigned code) {
        const unsigned idx = __hip_atomic_fetch_add(&bcnt[bb], 1u, __ATOMIC_RELAXED,
                                                    __HIP_MEMORY_SCOPE_AGENT);
        if (idx < (unsigned)MAXB) st_agent(&bucket[bb * MAXB + (int)idx], code);
    };
    auto classify = [&](int sn, int dn, unsigned bs, unsigned bd, int e) {
        const unsigned t = (unsigned)edge_type[e];
        const unsigned ps = bs ? hlookup(s.edge.hkey, s.edge.hval, sn) : 0u;
        const unsigned pd = bd ? hlookup(s.edge.hkey, s.edge.hval, dn) : 0u;
        const int hbs = (int)(ps & 0xFFFFu) - 1, tbs = (int)(ps >> 16) - 1;
        const int hbd = (int)(pd & 0xFFFFu) - 1, tbd = (int)(pd >> 16) - 1;
        const bool m5 = (hbs >= 0) && (hbs == tbd);
        const bool m6 = (hbd >= 0) && (hbd == tbs);
        if (hbd >= 0)        emit(hbd, (m6 ? 5u : 0u) * NUM_RELS + t);
        if (hbs >= 0)        emit(hbs, (m5 ? 4u : 1u) * NUM_RELS + t);
        if (tbd >= 0 && !m5) emit(tbd, 2u * NUM_RELS + t);
        if (tbs >= 0 && !m6) emit(tbs, 3u * NUM_RELS + t);
    };

    const int n4 = n_edges >> 2;
    const int sstr = EDGE_BLKS * BLOCK;
    const int et = eb * BLOCK + tid;
    const int4* src4 = (const int4*)edge_src;
    const int4* dst4 = (const int4*)edge_dst;
    for (int i = et; i < n4; i += sstr) {
        const int4 s4 = src4[i];
        const int4 d4 = dst4[i];
        #pragma unroll
        for (int j = 0; j < 4; ++j) {
            const int sn = (&s4.x)[j];
            const int dn = (&d4.x)[j];
            const unsigned bs = (s.edge.bm[sn >> 5] >> (sn & 31)) & 1u;
            const unsigned bd = (s.edge.bm[dn >> 5] >> (dn & 31)) & 1u;
            if (!(bs | bd)) continue;            // ~99% of edges: 2 LDS reads only
            classify(sn, dn, bs, bd, i * 4 + j);
        }
    }
    const int rem = n_edges & 3;
    if (et < rem) {
        const int e = n4 * 4 + et;
        const int sn = edge_src[e], dn = edge_dst[e];
        const unsigned bs = (s.edge.bm[sn >> 5] >> (sn & 31)) & 1u;
        const unsigned bd = (s.edge.bm[dn >> 5] >> (dn & 31)) & 1u;
        if (bs | bd) classify(sn, dn, bs, bd, e);
    }

    // ---- fence-free release + arrival ----
    asm volatile("s_waitcnt vmcnt(0)" ::: "memory");     // my emits (RMW+store) retired
    __syncthreads();                                     // all waves' emits retired
    if (tid == 0)
        __hip_atomic_fetch_add(done, 1u, __ATOMIC_RELAXED, __HIP_MEMORY_SCOPE_AGENT);

    // ---- final-phase prep, hidden under the wait (LDS safe: edge use is done)
    for (int i = tid; i < MODES * DIM; i += BLOCK) ((float*)s.fin.accf)[i] = 0.f;
    if (tid < MODES) s.fin.totf[tid] = 0.f;
    detect_dtype(rel_vectors, &s.fin.sflag);             // includes __syncthreads

    // ---- spin: agent-scope RMW poll (stale-proof, proven round 3) ----
    if (tid == 0) {
        while (__hip_atomic_fetch_add(done, 0u, __ATOMIC_RELAXED,
                                      __HIP_MEMORY_SCOPE_AGENT) < NPROD)
            __builtin_amdgcn_s_sleep(16);                // ~1024 cy between polls
    }
    __syncthreads();

    // ---- final phase: b = eb; read ONLY this b's bucket, one parallel round
    const int b = eb;
    const int mc = min((int)ld_agent_u(&bcnt[b]), MAXB);
    if (tid < mc) s.fin.mbuf[tid] = ld_agent_u(&bucket[b * MAXB + tid]);
    __syncthreads();

    // accumulate matched Y_rel rows; 8 half-wave groups over matches
    const int d = tid & 31;
    for (int j = tid >> 5; j < mc; j += 8) {
        const unsigned code = s.fin.mbuf[j];
        const int m = (int)(code / NUM_RELS);
        const int t = (int)(code % NUM_RELS);
        atomicAdd(&s.fin.accf[m][d], ld_agent_f(&Y_rel[(m * NUM_RELS + t) * DIM + d]));
        if (d == 0) atomicAdd(&s.fin.totf[m], 1.f);
    }
    __syncthreads();

    if (tid < DIM) {
        float rn = 0.f;
        for (int m = 0; m < MODES; ++m) rn += s.fin.accf[m][tid] / (s.fin.totf[m] + 1e-30f);
        s.fin.cat[tid] = rn / (float)MODES;
        s.fin.cat[DIM + tid] = ld_agent_f(&E_rel[rel_labels[b] * DIM + tid]);
    }
    __syncthreads();
    if (s.fin.sflag) epilogue_math<__hip_bfloat16>(s.fin.cat, conc_W, conc_b, fc_W, fc_b, out, b);
    else             epilogue_math<float>(s.fin.cat, conc_W, conc_b, fc_W, fc_b, out, b);
}

extern "C" void kernel_launch(void* const* d_in, const int* in_sizes, int n_in,
                              void* d_out, int out_size, void* d_ws, size_t ws_size,
                              hipStream_t stream) {
    const int* edge_src   = (const int*)d_in[0];
    const int* edge_dst   = (const int*)d_in[1];
    const int* edge_type  = (const int*)d_in[2];
    const int* head_ids   = (const int*)d_in[3];
    const int* tail_ids   = (const int*)d_in[4];
    const int* rel_labels = (const int*)d_in[5];
    const void* rel_vectors = d_in[6];
    const void* W1     = d_in[7];
    const void* b1     = d_in[8];
    const void* W2     = d_in[9];
    const void* b2     = d_in[10];
    const void* reld_W = d_in[11];
    const void* reld_b = d_in[12];
    const void* conc_W = d_in[13];
    const void* conc_b = d_in[14];
    const void* fc_W   = d_in[15];
    const void* fc_b   = d_in[16];

    const int n_edges = in_sizes[0];

    // workspace layout (~280 KB of ws): bucket consumed only below bcnt[b]
    // (slots written first); bcnt+done zeroed by the single 1 KB memset.
    unsigned* bucket = (unsigned*)d_ws;                  // BATCH * MAXB (128 KB)
    unsigned* bcnt   = bucket + BATCH * MAXB;            // BATCH
    unsigned* done   = bcnt + BATCH;                     // 1 (contiguous with bcnt)
    float*    E_rel  = (float*)(done + 1);               // NUM_RELS*DIM
    float*    Y_rel  = E_rel + NUM_RELS * DIM;           // MODES*NUM_RELS*DIM

    hipMemsetAsync(bcnt, 0, (BATCH + 1) * sizeof(unsigned), stream);  // ws is poisoned
    k_fused<<<NRB + EDGE_BLKS, BLOCK, 0, stream>>>(
        edge_src, edge_dst, edge_type, head_ids, tail_ids, rel_labels,
        rel_vectors, W1, b1, W2, b2, reld_W, reld_b,
        conc_W, conc_b, fc_W, fc_b,
        bucket, bcnt, E_rel, Y_rel, done, d_out, n_edges);
}

// Round 5
// 117.720 us; speedup vs baseline: 1.3817x; 1.0096x over previous
//
#include <hip/hip_runtime.h>
#include <hip/hip_bf16.h>

// Problem constants (fixed by the reference's setup_inputs).
constexpr int N_NODES  = 100000;
constexpr int BATCH    = 256;
constexpr int NUM_RELS = 200;
constexpr int VEC      = 300;
constexpr int DIM      = 32;
constexpr int MODES    = 6;

constexpr int BLOCK        = 1024;                    // 16 waves: latency-hiding (round-4 fix)
constexpr int BM_WORDS     = (N_NODES + 31) / 32;     // 3125 words = 12.5 KB (LDS)
constexpr int RELS_PER_BLK = 32;                      // one rel per 32-lane group
constexpr int NRB          = (NUM_RELS + RELS_PER_BLK - 1) / RELS_PER_BLK; // 7 (last partial)
constexpr int EDGE_BLKS    = 256;
constexpr int HASHN        = 1024;                    // LDS hash slots (load factor 0.5)
constexpr unsigned HEMPTY  = 0xFFFFFFFFu;
constexpr int MAXB         = 128;                     // codes per b: Poisson(~20), P(>128)~0
constexpr int BCNT_STR     = 32;                      // 1 counter per 128B line (kill RMW queueing)
constexpr unsigned NPROD   = NRB + EDGE_BLKS;         // 263 producer arrivals

// ---- agent-scope coherent accessors ----------------------------------------
// sc0+sc1 write-through stores / cache-bypassing loads. Every cross-block word
// moves through these => nothing cross-block is ever dirty in an L2 => no
// buffer_wbl2/buffer_inv (no __threadfence) needed anywhere. Release ordering
// is s_waitcnt vmcnt(0) + __syncthreads before the arrival add. Protocol
// HW-proven by rounds 3/4 (passed, absmax 0).
__device__ __forceinline__ void st_agent(float* p, float v) {
    __hip_atomic_store(p, v, __ATOMIC_RELAXED, __HIP_MEMORY_SCOPE_AGENT);
}
__device__ __forceinline__ void st_agent(unsigned* p, unsigned v) {
    __hip_atomic_store(p, v, __ATOMIC_RELAXED, __HIP_MEMORY_SCOPE_AGENT);
}
__device__ __forceinline__ float ld_agent_f(const float* p) {
    return __hip_atomic_load(p, __ATOMIC_RELAXED, __HIP_MEMORY_SCOPE_AGENT);
}
__device__ __forceinline__ unsigned ld_agent_u(const unsigned* p) {
    return __hip_atomic_load(p, __ATOMIC_RELAXED, __HIP_MEMORY_SCOPE_AGENT);
}

// ---- dtype-generic scalar load ---------------------------------------------
template <typename T> __device__ __forceinline__ float ldf(const void* p, int i);
template <> __device__ __forceinline__ float ldf<float>(const void* p, int i) {
    return ((const float*)p)[i];
}
template <> __device__ __forceinline__ float ldf<__hip_bfloat16>(const void* p, int i) {
    return __bfloat162float(((const __hip_bfloat16*)p)[i]);
}

// ---- per-block bf16-vs-fp32 detect (one ballot on wave 0) ------------------
__device__ __forceinline__ void detect_dtype(const void* rel_vectors, int* sflag) {
    const int tid = threadIdx.x;
    if (tid < 64) {
        unsigned short p = ((const unsigned short*)rel_vectors)[tid];
        unsigned long long mk = __ballot(((p >> 7) & 0xFF) > 140);
        if (tid == 0) *sflag = (mk == 0ull);
    }
    __syncthreads();
}

// ---- LDS hash: node id -> packed (head_b+1 | (tail_b+1)<<16) ---------------
__device__ __forceinline__ void hinsert(unsigned* hkey, unsigned* hval, int node, unsigned v) {
    unsigned h = ((unsigned)node * 2654435761u) >> 22;   // top 10 bits
    for (;;) {
        unsigned prev = atomicCAS(&hkey[h], HEMPTY, (unsigned)node);
        if (prev == HEMPTY || prev == (unsigned)node) { atomicOr(&hval[h], v); return; }
        h = (h + 1) & (HASHN - 1);
    }
}
__device__ __forceinline__ unsigned hlookup(const unsigned* hkey, const unsigned* hval, int node) {
    unsigned h = ((unsigned)node * 2654435761u) >> 22;
    for (;;) {
        const unsigned k = hkey[h];
        if (k == (unsigned)node) return hval[h];
        if (k == HEMPTY) return 0u;
        h = (h + 1) & (HASHN - 1);
    }
}

// ---- rel phase: E_rel[r] = mlp2(rel_vectors[r]); Y_rel[m][r] = E_rel[r]@reld_W[m]+reld_b[m]
// 32 groups x 32 lanes per 1024-thread block; tail block clamps r (redundant
// compute on r=199, stores predicated) so no divergent barrier hazard.
template <typename T>
__device__ __forceinline__ void rel_body(const void* rel_vectors, const void* W1, const void* b1,
                                         const void* W2, const void* b2,
                                         const void* reld_W, const void* reld_b,
                                         float* E_rel, float* Y_rel,
                                         float (*rv)[VEC], float (*e1)[DIM], float (*e2)[DIM],
                                         int r0) {
    const int tid = threadIdx.x;
    const int g = tid >> 5, d = tid & 31;
    const int r = r0 + g;
    const bool live = (r < NUM_RELS);
    const int rc = live ? r : (NUM_RELS - 1);    // clamped for loads/compute
    for (int v = d; v < VEC; v += 32) rv[g][v] = ldf<T>(rel_vectors, rc * VEC + v);
    __syncthreads();
    float acc = ldf<T>(b1, d);
    for (int v = 0; v < VEC; ++v) acc += rv[g][v] * ldf<T>(W1, v * DIM + d);
    e1[g][d] = acc;
    __syncthreads();
    float a2 = ldf<T>(b2, d);
    for (int k = 0; k < DIM; ++k) a2 += e1[g][k] * ldf<T>(W2, k * DIM + d);
    e2[g][d] = a2;
    if (live) st_agent(&E_rel[r * DIM + d], a2);
    __syncthreads();
    for (int m = 0; m < MODES; ++m) {
        float y = ldf<T>(reld_b, m * DIM + d);
        for (int k = 0; k < DIM; ++k) y += e2[g][k] * ldf<T>(reld_W, (m * DIM + k) * DIM + d);
        if (live) st_agent(&Y_rel[(m * NUM_RELS + r) * DIM + d], y);
    }
}

// ---- per-b epilogue math (final phase) -------------------------------------
template <typename T>
__device__ __forceinline__ void epilogue_math(const float* cat,
                                              const void* conc_W, const void* conc_b,
                                              const void* fc_W, const void* fc_b,
                                              void* out, int b) {
    const int tid = threadIdx.x;
    if (tid < DIM) {
        float h = ldf<T>(conc_b, tid);
        for (int k = 0; k < 2 * DIM; ++k) h += cat[k] * ldf<T>(conc_W, k * DIM + tid);
        h = fmaxf(h, 0.f);
        float n2 = h * h;
        #pragma unroll
        for (int off = 16; off >= 1; off >>= 1) n2 += __shfl_xor(n2, off);
        const float g = h / fmaxf(sqrtf(n2), 1e-12f);
        float pr = g * ldf<T>(fc_W, tid);
        #pragma unroll
        for (int off = 16; off >= 1; off >>= 1) pr += __shfl_xor(pr, off);
        if (tid == 0) {
            const float o = pr + ldf<T>(fc_b, 0);
            if constexpr (sizeof(T) == 2) ((__hip_bfloat16*)out)[b] = __float2bfloat16(o);
            else                          ((float*)out)[b] = o;
        }
    }
}

// ---- FUSED kernel, per-b buckets, 16-wave blocks ---------------------------
// bid < NRB           : rel MLP (32 rels/block), coherent stores, arrive, exit.
// bid in [NRB, +EDGE) : edge scan — at 1024 threads the 500K-edge scan is ONE
//                       int4-pair per thread (no grid-stride loop): the whole
//                       4MB read is a single coalesced latency round, vs
//                       round-4's 488 serialized rounds at ~1 wave/SIMD (the
//                       ~30us residual its counters exposed: 10% occupancy,
//                       2.3% VALUBusy). Emits go straight to target b's
//                       bucket; bcnt padded to 1 counter/128B line so emit
//                       RMWs don't queue 640-deep on 8 shared lines.
// Handshake: proven agent-RMW arrive/poll; final prep hoisted under the wait.
// Co-residency: 263 blocks, 16 waves => 2 blocks/CU by waves (512 slots),
// LDS 46.6KB => 3 blocks/CU by LDS. 263 <= 512: spin always terminates.
struct EdgeSmem {
    unsigned bm[BM_WORDS];
    unsigned hkey[HASHN];
    unsigned hval[HASHN];
};
struct RelSmem {
    float rv[RELS_PER_BLK][VEC];
    float e1[RELS_PER_BLK][DIM];
    float e2[RELS_PER_BLK][DIM];
    int sflag;
};
struct FinSmem {
    float    accf[MODES][DIM];
    float    totf[MODES];
    unsigned mbuf[MAXB];
    float    cat[2 * DIM];
    int      sflag;
};

__global__ __launch_bounds__(BLOCK) void k_fused(
        const int* __restrict__ edge_src, const int* __restrict__ edge_dst,
        const int* __restrict__ edge_type,
        const int* __restrict__ head_ids, const int* __restrict__ tail_ids,
        const int* __restrict__ rel_labels,
        const void* rel_vectors, const void* W1, const void* b1,
        const void* W2, const void* b2, const void* reld_W, const void* reld_b,
        const void* conc_W, const void* conc_b, const void* fc_W, const void* fc_b,
        unsigned* bucket, unsigned* bcnt, float* E_rel, float* Y_rel,
        unsigned* done, void* out, int n_edges) {
    union SmemU { RelSmem rel; EdgeSmem edge; FinSmem fin; };
    __shared__ SmemU s;
    const int bid = blockIdx.x, tid = threadIdx.x;

    if (bid < NRB) {
        detect_dtype(rel_vectors, &s.rel.sflag);
        const int r0 = bid * RELS_PER_BLK;
        if (s.rel.sflag)
            rel_body<__hip_bfloat16>(rel_vectors, W1, b1, W2, b2, reld_W, reld_b,
                                     E_rel, Y_rel, s.rel.rv, s.rel.e1, s.rel.e2, r0);
        else
            rel_body<float>(rel_vectors, W1, b1, W2, b2, reld_W, reld_b,
                            E_rel, Y_rel, s.rel.rv, s.rel.e1, s.rel.e2, r0);
        // release: every thread drains its write-through stores, barrier, arrive
        asm volatile("s_waitcnt vmcnt(0)" ::: "memory");
        __syncthreads();
        if (tid == 0)
            __hip_atomic_fetch_add(done, 1u, __ATOMIC_RELAXED, __HIP_MEMORY_SCOPE_AGENT);
        return;
    }

    // ---- edge phase ----
    const int eb = bid - NRB;
    for (int i = tid; i < BM_WORDS; i += BLOCK) s.edge.bm[i] = 0u;
    for (int i = tid; i < HASHN; i += BLOCK) { s.edge.hkey[i] = HEMPTY; s.edge.hval[i] = 0u; }
    __syncthreads();
    if (tid < BATCH) {
        const int h = head_ids[tid], t = tail_ids[tid];
        atomicOr(&s.edge.bm[h >> 5], 1u << (h & 31));
        atomicOr(&s.edge.bm[t >> 5], 1u << (t & 31));
        hinsert(s.edge.hkey, s.edge.hval, h, (unsigned)(tid + 1));
        hinsert(s.edge.hkey, s.edge.hval, t, (unsigned)(tid + 1) << 16);
    }
    __syncthreads();

    // emit a (mode, rel) code straight into target b's bucket (agent scope)
    auto emit = [&](int bb, unsigned code) {
        const unsigned idx = __hip_atomic_fetch_add(&bcnt[bb * BCNT_STR], 1u,
                                                    __ATOMIC_RELAXED,
                                                    __HIP_MEMORY_SCOPE_AGENT);
        if (idx < (unsigned)MAXB) st_agent(&bucket[bb * MAXB + (int)idx], code);
    };
    auto classify = [&](int sn, int dn, unsigned bs, unsigned bd, int e) {
        const unsigned t = (unsigned)edge_type[e];
        const unsigned ps = bs ? hlookup(s.edge.hkey, s.edge.hval, sn) : 0u;
        const unsigned pd = bd ? hlookup(s.edge.hkey, s.edge.hval, dn) : 0u;
        const int hbs = (int)(ps & 0xFFFFu) - 1, tbs = (int)(ps >> 16) - 1;
        const int hbd = (int)(pd & 0xFFFFu) - 1, tbd = (int)(pd >> 16) - 1;
        const bool m5 = (hbs >= 0) && (hbs == tbd);
        const bool m6 = (hbd >= 0) && (hbd == tbs);
        if (hbd >= 0)        emit(hbd, (m6 ? 5u : 0u) * NUM_RELS + t);
        if (hbs >= 0)        emit(hbs, (m5 ? 4u : 1u) * NUM_RELS + t);
        if (tbd >= 0 && !m5) emit(tbd, 2u * NUM_RELS + t);
        if (tbs >= 0 && !m6) emit(tbs, 3u * NUM_RELS + t);
    };

    // one int4-pair per thread: 262144 thread-slots cover n4=125000
    const int n4 = n_edges >> 2;
    const int sstr = EDGE_BLKS * BLOCK;
    const int et = eb * BLOCK + tid;
    const int4* src4 = (const int4*)edge_src;
    const int4* dst4 = (const int4*)edge_dst;
    for (int i = et; i < n4; i += sstr) {         // executes <= 1 iteration
        const int4 s4 = src4[i];
        const int4 d4 = dst4[i];
        #pragma unroll
        for (int j = 0; j < 4; ++j) {
            const int sn = (&s4.x)[j];
            const int dn = (&d4.x)[j];
            const unsigned bs = (s.edge.bm[sn >> 5] >> (sn & 31)) & 1u;
            const unsigned bd = (s.edge.bm[dn >> 5] >> (dn & 31)) & 1u;
            if (!(bs | bd)) continue;            // ~99% of edges: 2 LDS reads only
            classify(sn, dn, bs, bd, i * 4 + j);
        }
    }
    const int rem = n_edges & 3;
    if (et < rem) {
        const int e = n4 * 4 + et;
        const int sn = edge_src[e], dn = edge_dst[e];
        const unsigned bs = (s.edge.bm[sn >> 5] >> (sn & 31)) & 1u;
        const unsigned bd = (s.edge.bm[dn >> 5] >> (dn & 31)) & 1u;
        if (bs | bd) classify(sn, dn, bs, bd, e);
    }

    // ---- fence-free release + arrival ----
    asm volatile("s_waitcnt vmcnt(0)" ::: "memory");     // my emits (RMW+store) retired
    __syncthreads();                                     // all waves' emits retired
    if (tid == 0)
        __hip_atomic_fetch_add(done, 1u, __ATOMIC_RELAXED, __HIP_MEMORY_SCOPE_AGENT);

    // ---- final-phase prep, hidden under the wait (LDS safe: edge use is done)
    for (int i = tid; i < MODES * DIM; i += BLOCK) ((float*)s.fin.accf)[i] = 0.f;
    if (tid < MODES) s.fin.totf[tid] = 0.f;
    detect_dtype(rel_vectors, &s.fin.sflag);             // includes __syncthreads

    // ---- spin: agent-scope RMW poll (stale-proof, proven rounds 3/4) ----
    if (tid == 0) {
        while (__hip_atomic_fetch_add(done, 0u, __ATOMIC_RELAXED,
                                      __HIP_MEMORY_SCOPE_AGENT) < NPROD)
            __builtin_amdgcn_s_sleep(32);                // ~2048 cy between polls
    }
    __syncthreads();

    // ---- final phase: b = eb; read ONLY this b's bucket, one parallel round
    const int b = eb;
    const int mc = min((int)ld_agent_u(&bcnt[b * BCNT_STR]), MAXB);
    if (tid < mc) s.fin.mbuf[tid] = ld_agent_u(&bucket[b * MAXB + tid]);
    __syncthreads();

    // accumulate matched Y_rel rows; 32 half-wave groups over matches
    const int d = tid & 31;
    for (int j = tid >> 5; j < mc; j += BLOCK / 32) {
        const unsigned code = s.fin.mbuf[j];
        const int m = (int)(code / NUM_RELS);
        const int t = (int)(code % NUM_RELS);
        atomicAdd(&s.fin.accf[m][d], ld_agent_f(&Y_rel[(m * NUM_RELS + t) * DIM + d]));
        if (d == 0) atomicAdd(&s.fin.totf[m], 1.f);
    }
    __syncthreads();

    if (tid < DIM) {
        float rn = 0.f;
        for (int m = 0; m < MODES; ++m) rn += s.fin.accf[m][tid] / (s.fin.totf[m] + 1e-30f);
        s.fin.cat[tid] = rn / (float)MODES;
        s.fin.cat[DIM + tid] = ld_agent_f(&E_rel[rel_labels[b] * DIM + tid]);
    }
    __syncthreads();
    if (s.fin.sflag) epilogue_math<__hip_bfloat16>(s.fin.cat, conc_W, conc_b, fc_W, fc_b, out, b);
    else             epilogue_math<float>(s.fin.cat, conc_W, conc_b, fc_W, fc_b, out, b);
}

extern "C" void kernel_launch(void* const* d_in, const int* in_sizes, int n_in,
                              void* d_out, int out_size, void* d_ws, size_t ws_size,
                              hipStream_t stream) {
    const int* edge_src   = (const int*)d_in[0];
    const int* edge_dst   = (const int*)d_in[1];
    const int* edge_type  = (const int*)d_in[2];
    const int* head_ids   = (const int*)d_in[3];
    const int* tail_ids   = (const int*)d_in[4];
    const int* rel_labels = (const int*)d_in[5];
    const void* rel_vectors = d_in[6];
    const void* W1     = d_in[7];
    const void* b1     = d_in[8];
    const void* W2     = d_in[9];
    const void* b2     = d_in[10];
    const void* reld_W = d_in[11];
    const void* reld_b = d_in[12];
    const void* conc_W = d_in[13];
    const void* conc_b = d_in[14];
    const void* fc_W   = d_in[15];
    const void* fc_b   = d_in[16];

    const int n_edges = in_sizes[0];

    // workspace layout (~340 KB of ws): bucket slots consumed only below
    // bcnt[b] (written first); bcnt_pad + done zeroed by the single memset.
    unsigned* bucket = (unsigned*)d_ws;                  // BATCH * MAXB (128 KB)
    unsigned* bcnt   = bucket + BATCH * MAXB;            // BATCH counters, 128B-strided (32 KB)
    unsigned* done   = bcnt + BATCH * BCNT_STR;          // 1 word (own cache line)
    float*    E_rel  = (float*)(done + 32);              // NUM_RELS*DIM
    float*    Y_rel  = E_rel + NUM_RELS * DIM;           // MODES*NUM_RELS*DIM

    hipMemsetAsync(bcnt, 0, (BATCH * BCNT_STR + 1) * sizeof(unsigned), stream);
    k_fused<<<NRB + EDGE_BLKS, BLOCK, 0, stream>>>(
        edge_src, edge_dst, edge_type, head_ids, tail_ids, rel_labels,
        rel_vectors, W1, b1, W2, b2, reld_W, reld_b,
        conc_W, conc_b, fc_W, fc_b,
        bucket, bcnt, E_rel, Y_rel, done, d_out, n_edges);
}

// Round 6
// 114.307 us; speedup vs baseline: 1.4230x; 1.0299x over previous
//
#include <hip/hip_runtime.h>
#include <hip/hip_bf16.h>

// Problem constants (fixed by the reference's setup_inputs).
constexpr int N_NODES  = 100000;
constexpr int BATCH    = 256;
constexpr int NUM_RELS = 200;
constexpr int VEC      = 300;
constexpr int DIM      = 32;
constexpr int MODES    = 6;

constexpr int BLOCK        = 1024;                    // k1: 16 waves, one-round edge scan
constexpr int BM_WORDS     = (N_NODES + 31) / 32;     // 3125 words = 12.5 KB (LDS)
constexpr int RELS_PER_BLK = 32;                      // one rel per 32-lane group
constexpr int NRB          = (NUM_RELS + RELS_PER_BLK - 1) / RELS_PER_BLK; // 7 (last partial)
constexpr int EDGE_BLKS    = 256;
constexpr int HASHN        = 1024;                    // LDS hash slots (load factor 0.5)
constexpr unsigned HEMPTY  = 0xFFFFFFFFu;
constexpr int MAXB         = 128;                     // codes per b: Poisson(~20), P(>128)~0

// ---- dtype-generic scalar load ---------------------------------------------
template <typename T> __device__ __forceinline__ float ldf(const void* p, int i);
template <> __device__ __forceinline__ float ldf<float>(const void* p, int i) {
    return ((const float*)p)[i];
}
template <> __device__ __forceinline__ float ldf<__hip_bfloat16>(const void* p, int i) {
    return __bfloat162float(((const __hip_bfloat16*)p)[i]);
}

// ---- per-block bf16-vs-fp32 detect (one ballot on wave 0) ------------------
__device__ __forceinline__ void detect_dtype(const void* rel_vectors, int* sflag) {
    const int tid = threadIdx.x;
    if (tid < 64) {
        unsigned short p = ((const unsigned short*)rel_vectors)[tid];
        unsigned long long mk = __ballot(((p >> 7) & 0xFF) > 140);
        if (tid == 0) *sflag = (mk == 0ull);
    }
    __syncthreads();
}

// ---- LDS hash: node id -> packed (head_b+1 | (tail_b+1)<<16) ---------------
__device__ __forceinline__ void hinsert(unsigned* hkey, unsigned* hval, int node, unsigned v) {
    unsigned h = ((unsigned)node * 2654435761u) >> 22;   // top 10 bits
    for (;;) {
        unsigned prev = atomicCAS(&hkey[h], HEMPTY, (unsigned)node);
        if (prev == HEMPTY || prev == (unsigned)node) { atomicOr(&hval[h], v); return; }
        h = (h + 1) & (HASHN - 1);
    }
}
__device__ __forceinline__ unsigned hlookup(const unsigned* hkey, const unsigned* hval, int node) {
    unsigned h = ((unsigned)node * 2654435761u) >> 22;
    for (;;) {
        const unsigned k = hkey[h];
        if (k == (unsigned)node) return hval[h];
        if (k == HEMPTY) return 0u;
        h = (h + 1) & (HASHN - 1);
    }
}

// ---- rel phase: E_rel[r] = mlp2(rel_vectors[r]); Y_rel[m][r] = E_rel[r]@reld_W[m]+reld_b[m]
// 32 groups x 32 lanes per 1024-thread block; tail block clamps r (redundant
// compute on r=199, stores predicated) so no divergent barrier hazard.
// Plain stores: k2 runs after the kernel boundary, which provides coherence.
template <typename T>
__device__ __forceinline__ void rel_body(const void* rel_vectors, const void* W1, const void* b1,
                                         const void* W2, const void* b2,
                                         const void* reld_W, const void* reld_b,
                                         float* E_rel, float* Y_rel,
                                         float (*rv)[VEC], float (*e1)[DIM], float (*e2)[DIM],
                                         int r0) {
    const int tid = threadIdx.x;
    const int g = tid >> 5, d = tid & 31;
    const int r = r0 + g;
    const bool live = (r < NUM_RELS);
    const int rc = live ? r : (NUM_RELS - 1);    // clamped for loads/compute
    for (int v = d; v < VEC; v += 32) rv[g][v] = ldf<T>(rel_vectors, rc * VEC + v);
    __syncthreads();
    float acc = ldf<T>(b1, d);
    for (int v = 0; v < VEC; ++v) acc += rv[g][v] * ldf<T>(W1, v * DIM + d);
    e1[g][d] = acc;
    __syncthreads();
    float a2 = ldf<T>(b2, d);
    for (int k = 0; k < DIM; ++k) a2 += e1[g][k] * ldf<T>(W2, k * DIM + d);
    e2[g][d] = a2;
    if (live) E_rel[r * DIM + d] = a2;
    __syncthreads();
    for (int m = 0; m < MODES; ++m) {
        float y = ldf<T>(reld_b, m * DIM + d);
        for (int k = 0; k < DIM; ++k) y += e2[g][k] * ldf<T>(reld_W, (m * DIM + k) * DIM + d);
        if (live) Y_rel[(m * NUM_RELS + r) * DIM + d] = y;
    }
}

// ---- per-b epilogue math ---------------------------------------------------
template <typename T>
__device__ __forceinline__ void epilogue_math(const float* cat,
                                              const void* conc_W, const void* conc_b,
                                              const void* fc_W, const void* fc_b,
                                              void* out, int b) {
    const int tid = threadIdx.x;
    if (tid < DIM) {
        float h = ldf<T>(conc_b, tid);
        for (int k = 0; k < 2 * DIM; ++k) h += cat[k] * ldf<T>(conc_W, k * DIM + tid);
        h = fmaxf(h, 0.f);
        float n2 = h * h;
        #pragma unroll
        for (int off = 16; off >= 1; off >>= 1) n2 += __shfl_xor(n2, off);
        const float g = h / fmaxf(sqrtf(n2), 1e-12f);
        float pr = g * ldf<T>(fc_W, tid);
        #pragma unroll
        for (int off = 16; off >= 1; off >>= 1) pr += __shfl_xor(pr, off);
        if (tid == 0) {
            const float o = pr + ldf<T>(fc_b, 0);
            if constexpr (sizeof(T) == 2) ((__hip_bfloat16*)out)[b] = __float2bfloat16(o);
            else                          ((float*)out)[b] = o;
        }
    }
}

// ---- K1: rel MLP + edge scan with direct per-b bucket emit -----------------
// Two-kernel structure deliberately REINSTATED: rounds 3-5 showed the fused
// grid handshake's same-word RMW poll (256 agent-scope fetch_adds serializing
// at one MALL slice every ~0.85us) costs ~25us — far more than the ~5-10us
// launch it saved. The kernel boundary gives cross-block coherence for free,
// so all agent-scope/coherent ops are gone: plain cached stores + default
// device-scope atomicAdd.
// bid < NRB           : rel MLP (32 rels/block).
// bid in [NRB, +EDGE) : 1024-thread edge scan — one int4-pair per thread
//                       (262144 slots >= 125000), i.e. the whole 4MB read is
//                       one coalesced latency round. Each classified edge
//                       emits its (mode,rel) code straight into target b's
//                       bucket: no per-block lists, no O(total) rescan in k2.
struct EdgeSmem {
    unsigned bm[BM_WORDS];
    unsigned hkey[HASHN];
    unsigned hval[HASHN];
};
struct RelSmem {
    float rv[RELS_PER_BLK][VEC];
    float e1[RELS_PER_BLK][DIM];
    float e2[RELS_PER_BLK][DIM];
    int sflag;
};

__global__ __launch_bounds__(BLOCK) void k_main(
        const int* __restrict__ edge_src, const int* __restrict__ edge_dst,
        const int* __restrict__ edge_type,
        const int* __restrict__ head_ids, const int* __restrict__ tail_ids,
        const void* rel_vectors, const void* W1, const void* b1,
        const void* W2, const void* b2, const void* reld_W, const void* reld_b,
        unsigned* __restrict__ bucket, unsigned* __restrict__ bcnt,
        float* __restrict__ E_rel, float* __restrict__ Y_rel, int n_edges) {
    union SmemU { RelSmem rel; EdgeSmem edge; };
    __shared__ SmemU s;
    const int bid = blockIdx.x, tid = threadIdx.x;

    if (bid < NRB) {
        detect_dtype(rel_vectors, &s.rel.sflag);
        const int r0 = bid * RELS_PER_BLK;
        if (s.rel.sflag)
            rel_body<__hip_bfloat16>(rel_vectors, W1, b1, W2, b2, reld_W, reld_b,
                                     E_rel, Y_rel, s.rel.rv, s.rel.e1, s.rel.e2, r0);
        else
            rel_body<float>(rel_vectors, W1, b1, W2, b2, reld_W, reld_b,
                            E_rel, Y_rel, s.rel.rv, s.rel.e1, s.rel.e2, r0);
        return;
    }

    // ---- edge block ----
    const int eb = bid - NRB;
    for (int i = tid; i < BM_WORDS; i += BLOCK) s.edge.bm[i] = 0u;
    for (int i = tid; i < HASHN; i += BLOCK) { s.edge.hkey[i] = HEMPTY; s.edge.hval[i] = 0u; }
    __syncthreads();
    if (tid < BATCH) {
        const int h = head_ids[tid], t = tail_ids[tid];
        atomicOr(&s.edge.bm[h >> 5], 1u << (h & 31));
        atomicOr(&s.edge.bm[t >> 5], 1u << (t & 31));
        hinsert(s.edge.hkey, s.edge.hval, h, (unsigned)(tid + 1));
        hinsert(s.edge.hkey, s.edge.hval, t, (unsigned)(tid + 1) << 16);
    }
    __syncthreads();

    // emit a (mode, rel) code straight into target b's bucket (device-scope
    // atomicAdd; ~5K emits over 256 cached counters — negligible contention)
    auto emit = [&](int bb, unsigned code) {
        const unsigned idx = atomicAdd(&bcnt[bb], 1u);
        if (idx < (unsigned)MAXB) bucket[bb * MAXB + (int)idx] = code;
    };
    auto classify = [&](int sn, int dn, unsigned bs, unsigned bd, int e) {
        const unsigned t = (unsigned)edge_type[e];
        const unsigned ps = bs ? hlookup(s.edge.hkey, s.edge.hval, sn) : 0u;
        const unsigned pd = bd ? hlookup(s.edge.hkey, s.edge.hval, dn) : 0u;
        const int hbs = (int)(ps & 0xFFFFu) - 1, tbs = (int)(ps >> 16) - 1;
        const int hbd = (int)(pd & 0xFFFFu) - 1, tbd = (int)(pd >> 16) - 1;
        const bool m5 = (hbs >= 0) && (hbs == tbd);
        const bool m6 = (hbd >= 0) && (hbd == tbs);
        if (hbd >= 0)        emit(hbd, (m6 ? 5u : 0u) * NUM_RELS + t);
        if (hbs >= 0)        emit(hbs, (m5 ? 4u : 1u) * NUM_RELS + t);
        if (tbd >= 0 && !m5) emit(tbd, 2u * NUM_RELS + t);
        if (tbs >= 0 && !m6) emit(tbs, 3u * NUM_RELS + t);
    };

    // one int4-pair per thread: 262144 thread-slots cover n4=125000
    const int n4 = n_edges >> 2;
    const int sstr = EDGE_BLKS * BLOCK;
    const int et = eb * BLOCK + tid;
    const int4* src4 = (const int4*)edge_src;
    const int4* dst4 = (const int4*)edge_dst;
    for (int i = et; i < n4; i += sstr) {         // executes <= 1 iteration here
        const int4 s4 = src4[i];
        const int4 d4 = dst4[i];
        #pragma unroll
        for (int j = 0; j < 4; ++j) {
            const int sn = (&s4.x)[j];
            const int dn = (&d4.x)[j];
            const unsigned bs = (s.edge.bm[sn >> 5] >> (sn & 31)) & 1u;
            const unsigned bd = (s.edge.bm[dn >> 5] >> (dn & 31)) & 1u;
            if (!(bs | bd)) continue;            // ~99% of edges: 2 LDS reads only
            classify(sn, dn, bs, bd, i * 4 + j);
        }
    }
    const int rem = n_edges & 3;
    if (et < rem) {
        const int e = n4 * 4 + et;
        const int sn = edge_src[e], dn = edge_dst[e];
        const unsigned bs = (s.edge.bm[sn >> 5] >> (sn & 31)) & 1u;
        const unsigned bd = (s.edge.bm[dn >> 5] >> (dn & 31)) & 1u;
        if (bs | bd) classify(sn, dn, bs, bd, e);
    }
}

// ---- K2: per-b epilogue. Reads only b's own bucket (<= ~45 codes), cached --
__global__ __launch_bounds__(256) void k_final(
        const unsigned* __restrict__ bucket, const unsigned* __restrict__ bcnt,
        const float* __restrict__ E_rel, const float* __restrict__ Y_rel,
        const int* __restrict__ rel_labels, const void* rel_vectors,
        const void* conc_W, const void* conc_b, const void* fc_W, const void* fc_b,
        void* out) {
    __shared__ float    accf[MODES][DIM];
    __shared__ float    totf[MODES];
    __shared__ unsigned mbuf[MAXB];
    __shared__ float    cat[2 * DIM];
    __shared__ int      sflag;
    const int b = blockIdx.x, tid = threadIdx.x;

    for (int i = tid; i < MODES * DIM; i += 256) ((float*)accf)[i] = 0.f;
    if (tid < MODES) totf[tid] = 0.f;
    const int mc = min((int)bcnt[b], MAXB);
    if (tid < mc) mbuf[tid] = bucket[b * MAXB + tid];
    detect_dtype(rel_vectors, &sflag);           // includes __syncthreads

    // accumulate matched Y_rel rows; 8 half-wave groups over matches (cached)
    const int d = tid & 31;
    for (int j = tid >> 5; j < mc; j += 8) {
        const unsigned code = mbuf[j];
        const int m = (int)(code / NUM_RELS);
        const int t = (int)(code % NUM_RELS);
        atomicAdd(&accf[m][d], Y_rel[(m * NUM_RELS + t) * DIM + d]);
        if (d == 0) atomicAdd(&totf[m], 1.f);
    }
    __syncthreads();

    if (tid < DIM) {
        float rn = 0.f;
        for (int m = 0; m < MODES; ++m) rn += accf[m][tid] / (totf[m] + 1e-30f);
        cat[tid] = rn / (float)MODES;
        cat[DIM + tid] = E_rel[rel_labels[b] * DIM + tid];
    }
    __syncthreads();
    if (sflag) epilogue_math<__hip_bfloat16>(cat, conc_W, conc_b, fc_W, fc_b, out, b);
    else       epilogue_math<float>(cat, conc_W, conc_b, fc_W, fc_b, out, b);
}

extern "C" void kernel_launch(void* const* d_in, const int* in_sizes, int n_in,
                              void* d_out, int out_size, void* d_ws, size_t ws_size,
                              hipStream_t stream) {
    const int* edge_src   = (const int*)d_in[0];
    const int* edge_dst   = (const int*)d_in[1];
    const int* edge_type  = (const int*)d_in[2];
    const int* head_ids   = (const int*)d_in[3];
    const int* tail_ids   = (const int*)d_in[4];
    const int* rel_labels = (const int*)d_in[5];
    const void* rel_vectors = d_in[6];
    const void* W1     = d_in[7];
    const void* b1     = d_in[8];
    const void* W2     = d_in[9];
    const void* b2     = d_in[10];
    const void* reld_W = d_in[11];
    const void* reld_b = d_in[12];
    const void* conc_W = d_in[13];
    const void* conc_b = d_in[14];
    const void* fc_W   = d_in[15];
    const void* fc_b   = d_in[16];

    const int n_edges = in_sizes[0];

    // workspace layout (~285 KB of ws): bucket slots consumed only below
    // bcnt[b] (written first in k_main); bcnt zeroed by the 1 KB memset.
    unsigned* bucket = (unsigned*)d_ws;                  // BATCH * MAXB (128 KB)
    unsigned* bcnt   = bucket + BATCH * MAXB;            // BATCH (1 KB, packed)
    float*    E_rel  = (float*)(bcnt + BATCH);           // NUM_RELS*DIM
    float*    Y_rel  = E_rel + NUM_RELS * DIM;           // MODES*NUM_RELS*DIM

    hipMemsetAsync(bcnt, 0, BATCH * sizeof(unsigned), stream);  // ws is poisoned each iter
    k_main<<<NRB + EDGE_BLKS, BLOCK, 0, stream>>>(
        edge_src, edge_dst, edge_type, head_ids, tail_ids,
        rel_vectors, W1, b1, W2, b2, reld_W, reld_b,
        bucket, bcnt, E_rel, Y_rel, n_edges);
    k_final<<<BATCH, 256, 0, stream>>>(
        bucket, bcnt, E_rel, Y_rel, rel_labels, rel_vectors,
        conc_W, conc_b, fc_W, fc_b, d_out);
}